// Round 4
// baseline (81.198 us; speedup 1.0000x reference)
//
#include <hip/hip_runtime.h>

#define BSZ 32
#define NN 512
#define INF 256
#define OUTF 128
#define NH 4
#define HD 512
#define NEG_SLOPE 0.2f

typedef __attribute__((ext_vector_type(8))) short bf16x8;
typedef __attribute__((ext_vector_type(8))) unsigned short ushort8;
typedef __attribute__((ext_vector_type(4))) float f32x4;

static __device__ __forceinline__ unsigned short f2bf(float f) {
    unsigned u = __builtin_bit_cast(unsigned, f);
    return (unsigned short)((u + 0x7FFFu + ((u >> 16) & 1u)) >> 16);
}

// ---- pack x -> bf16 row-major [16384][256] ----
__global__ __launch_bounds__(256) void kpack_x(const float* __restrict__ x,
                                               unsigned short* __restrict__ xb) {
    int gid = blockIdx.x * 256 + threadIdx.x;
    const float4* xv = (const float4*)x;
    float4 a = xv[gid * 2], b = xv[gid * 2 + 1];
    ushort8 o;
    o[0]=f2bf(a.x); o[1]=f2bf(a.y); o[2]=f2bf(a.z); o[3]=f2bf(a.w);
    o[4]=f2bf(b.x); o[5]=f2bf(b.y); o[6]=f2bf(b.z); o[7]=f2bf(b.w);
    *(ushort8*)(xb + (size_t)gid * 8) = o;
}

// ---- pack w[256][512] -> wB frag layout ((kb*4+g)*512 + c)*8 + e, k=kb*32+g*8+e ----
__global__ __launch_bounds__(256) void kpack_w(const float* __restrict__ w,
                                               unsigned short* __restrict__ wB) {
    int gid = blockIdx.x * 256 + threadIdx.x;
    int c = gid & 511, k = gid >> 9;
    int kb = k >> 5, g = (k >> 3) & 3, e = k & 7;
    wB[(((size_t)(kb * 4 + g) * 512) + c) * 8 + e] = f2bf(w[(size_t)k * 512 + c]);
}

// ---- projection GEMM (MFMA) + coeffs; hB written via LDS-staged wide stores ----
__global__ __launch_bounds__(256) void k_proj(
    const unsigned short* __restrict__ xb, const unsigned short* __restrict__ wB,
    const float* __restrict__ ai, const float* __restrict__ aj,
    unsigned short* __restrict__ hB, float* __restrict__ ciT, float* __restrict__ cjT)
{
    __shared__ unsigned short hs[NH * 4096];           // 32 KB, hB slab image
    const int tid = threadIdx.x;
    const int lane = tid & 63, head = tid >> 6;
    const int l15 = lane & 15, g = lane >> 4;
    const int row0 = blockIdx.x * 32;

    f32x4 acc[2][8] = {};
    const unsigned short* ap0 = xb + (size_t)(row0 + l15) * INF + g * 8;
    const unsigned short* ap1 = ap0 + 16 * INF;
    const unsigned short* bp  = wB + ((size_t)g * 512 + head * 128 + l15) * 8;

    #pragma unroll
    for (int kb = 0; kb < 8; ++kb) {
        bf16x8 a0 = *(const bf16x8*)(ap0 + kb * 32);
        bf16x8 a1 = *(const bf16x8*)(ap1 + kb * 32);
        #pragma unroll
        for (int nf = 0; nf < 8; ++nf) {
            bf16x8 bv = *(const bf16x8*)(bp + (size_t)kb * 16384 + nf * 128);
            acc[0][nf] = __builtin_amdgcn_mfma_f32_16x16x32_bf16(a0, bv, acc[0][nf], 0, 0, 0);
            acc[1][nf] = __builtin_amdgcn_mfma_f32_16x16x32_bf16(a1, bv, acc[1][nf], 0, 0, 0);
        }
    }

    float aiv[8], ajv[8];
    #pragma unroll
    for (int nf = 0; nf < 8; ++nf) {
        aiv[nf] = ai[head * 128 + nf * 16 + l15];
        ajv[nf] = aj[head * 128 + nf * 16 + l15];
    }
    const int b = row0 >> 9;
    const int nloc0 = row0 & 511;
    const int kb2 = nloc0 >> 5;

    #pragma unroll
    for (int m = 0; m < 2; ++m) {
        float pi[4] = {0,0,0,0}, pj[4] = {0,0,0,0};
        #pragma unroll
        for (int nf = 0; nf < 8; ++nf)
            #pragma unroll
            for (int reg = 0; reg < 4; ++reg) {
                pi[reg] = fmaf(acc[m][nf][reg], aiv[nf], pi[reg]);
                pj[reg] = fmaf(acc[m][nf][reg], ajv[nf], pj[reg]);
            }
        #pragma unroll
        for (int reg = 0; reg < 4; ++reg) {
            #pragma unroll
            for (int off = 1; off < 16; off <<= 1) {
                pi[reg] += __shfl_xor(pi[reg], off);
                pj[reg] += __shfl_xor(pj[reg], off);
            }
        }
        if (l15 == 0) {
            #pragma unroll
            for (int reg = 0; reg < 4; ++reg) {
                int n = nloc0 + 16 * m + 4 * g + reg;
                ciT[((size_t)(head * BSZ + b) * NN) + n] = pi[reg];
                cjT[((size_t)(head * BSZ + b) * NN) + n] = pj[reg];
            }
        }
        // stage hB slab in LDS: hs[head][(g2*128 + dd)*8 + e], jloc = 16m+4g+reg
        #pragma unroll
        for (int reg = 0; reg < 4; ++reg) {
            int jloc = 16 * m + 4 * g + reg;
            int g2 = (jloc >> 3) & 3, e = jloc & 7;
            #pragma unroll
            for (int nf = 0; nf < 8; ++nf)
                hs[head * 4096 + (g2 * 128 + nf * 16 + l15) * 8 + e] =
                    f2bf(acc[m][nf][reg]);
        }
    }
    __syncthreads();
    {   // cooperative coalesced store: per head one contiguous 8 KB slab
        ushort8* dst = (ushort8*)(hB + (((size_t)(b * 4 + head) * 16 + kb2) * 4096));
        const ushort8* src = (const ushort8*)(hs + head * 4096);
        #pragma unroll
        for (int it = 0; it < 8; ++it)
            dst[it * 64 + lane] = src[it * 64 + lane];
    }
}

// ---- fused masked-softmax attention + MFMA aggregation ----
// 512 thr; 2 stages of 2 heads through a 32 KB att buffer. Single-pass softmax
// using per-(b,h) upper bound M_h (shift-invariant); 1/sum folded into epilogue.
__global__ __launch_bounds__(512, 6) void k_attn(
    const float* __restrict__ adj, const unsigned short* __restrict__ hB,
    const float* __restrict__ ciT, const float* __restrict__ cjT,
    const float* __restrict__ bias, float* __restrict__ out)
{
    __shared__ __align__(16) float cj_s[NH][NN];              // 8 KB
    __shared__ float ci_s[NH][16];
    __shared__ unsigned long long mask_s[16][8];              // 1 KB
    __shared__ float M_s[NH];
    __shared__ float is_s[NH][16];
    __shared__ __align__(16) unsigned short att_s[2 * 16 * NN]; // 32 KB

    const int tid = threadIdx.x;
    const int lane = tid & 63, wave = tid >> 6;
    const int orig = blockIdx.x;
    const int swz = (orig & 7) * 128 + (orig >> 3);   // 1024 % 8 == 0, bijective
    const int b = swz >> 5;
    const int i0 = (swz & 31) * 16;

    #pragma unroll
    for (int hh = 0; hh < NH; ++hh)
        cj_s[hh][tid] = cjT[(size_t)(hh * BSZ + b) * NN + tid];
    if (tid < 64) {
        int r = tid & 15, hh = tid >> 4;
        ci_s[hh][r] = ciT[(size_t)(hh * BSZ + b) * NN + i0 + r];
    }
    #pragma unroll
    for (int rr = 0; rr < 2; ++rr) {
        int r = wave * 2 + rr;
        const float* arow = adj + (size_t)(b * NN + i0 + r) * NN;
        #pragma unroll
        for (int t = 0; t < 8; ++t) {
            unsigned long long msk = __ballot(arow[t * 64 + lane] > 0.f);
            if (lane == 0) mask_s[r][t] = msk;
        }
    }
    __syncthreads();

    if (wave < NH) {   // M_h = unmasked max_j cj[h][j] (upper bound for stabilizer)
        float mv = -1e30f;
        #pragma unroll
        for (int c = 0; c < 8; ++c) mv = fmaxf(mv, cj_s[wave][c * 64 + lane]);
        #pragma unroll
        for (int off = 32; off; off >>= 1) mv = fmaxf(mv, __shfl_xor(mv, off));
        if (lane == 0) M_s[wave] = mv;
    }
    __syncthreads();

    const int l15 = lane & 15, g = lane >> 4;
    const int hl = wave >> 2;           // local head (0/1) within stage
    const int q = wave & 3;

    #pragma unroll
    for (int stage = 0; stage < 2; ++stage) {
        const int hh = stage * 2 + hl;
        // ---- phase 1: single-pass exp + sum, rows q*4 .. q*4+3 of head hh
        const int r0 = q * 4;
        #pragma unroll
        for (int rr = 0; rr < 4; ++rr) {
            const int r = r0 + rr;
            const unsigned long long* mrow = mask_s[r];
            const float basec = ci_s[hh][r];
            float sm = basec + M_s[hh];
            const float m = sm > 0.f ? sm : NEG_SLOPE * sm;
            float sv = 0.f;
            char* abase = ((char*)att_s) + hl * 16384 + r * 1024;
            const int rx = (r & 7) << 4;
            #pragma unroll
            for (int c = 0; c < 4; ++c) {
                int j2 = c * 128 + lane * 2;
                float2 cv = *(const float2*)&cj_s[hh][j2];
                unsigned bb = (unsigned)((mrow[j2 >> 6] >> (j2 & 63)) & 3ull);
                float s0 = basec + cv.x; s0 = s0 > 0.f ? s0 : NEG_SLOPE * s0;
                float s1 = basec + cv.y; s1 = s1 > 0.f ? s1 : NEG_SLOPE * s1;
                float p0 = __expf(s0 - m); p0 = (bb & 1u) ? p0 : 0.f;
                float p1 = __expf(s1 - m); p1 = (bb & 2u) ? p1 : 0.f;
                sv += p0 + p1;
                unsigned pk = (unsigned)f2bf(p0) | ((unsigned)f2bf(p1) << 16);
                *(unsigned*)(abase + ((j2 * 2) ^ rx)) = pk;
            }
            #pragma unroll
            for (int off = 32; off; off >>= 1) sv += __shfl_xor(sv, off);
            if (lane == 0) is_s[hh][r] = sv > 0.f ? 1.f / sv : 0.f;
        }
        __syncthreads();

        // ---- phase 2: MFMA aggregation; wave covers nf = q*2 .. q*2+1 of head hh
        f32x4 acc2[2] = {};
        const unsigned short* hbp = hB + (size_t)(b * 4 + hh) * 65536
                                       + g * 1024 + q * 256 + l15 * 8;
        const char* ab = ((const char*)att_s) + hl * 16384 + l15 * 1024;
        const int rx2 = (l15 & 7) << 4;
        #pragma unroll
        for (int kb = 0; kb < 16; ++kb) {
            bf16x8 av = *(const bf16x8*)(ab + ((kb * 64 + g * 16) ^ rx2));
            #pragma unroll
            for (int nfl = 0; nfl < 2; ++nfl) {
                bf16x8 bv = *(const bf16x8*)(hbp + (size_t)kb * 4096 + nfl * 128);
                acc2[nfl] = __builtin_amdgcn_mfma_f32_16x16x32_bf16(av, bv, acc2[nfl], 0, 0, 0);
            }
        }
        #pragma unroll
        for (int nfl = 0; nfl < 2; ++nfl) {
            int colg = hh * 128 + (q * 2 + nfl) * 16 + l15;
            float bvv = bias[colg];
            #pragma unroll
            for (int reg = 0; reg < 4; ++reg) {
                int i = g * 4 + reg;
                out[(size_t)(b * NN + i0 + i) * HD + colg] =
                    acc2[nfl][reg] * is_s[hh][i] + bvv;
            }
        }
        __syncthreads();   // att_s reused by next stage
    }
}

extern "C" void kernel_launch(void* const* d_in, const int* in_sizes, int n_in,
                              void* d_out, int out_size, void* d_ws, size_t ws_size,
                              hipStream_t stream)
{
    const float* x    = (const float*)d_in[0];
    const float* adj  = (const float*)d_in[1];
    const float* w    = (const float*)d_in[2];
    const float* ai   = (const float*)d_in[3];
    const float* aj   = (const float*)d_in[4];
    const float* bias = (const float*)d_in[5];
    float* out = (float*)d_out;

    char* ws = (char*)d_ws;
    unsigned short* xb = (unsigned short*)ws;                       // 8,388,608 B
    unsigned short* wB = (unsigned short*)(ws + 8388608);           //   262,144 B
    unsigned short* hB = (unsigned short*)(ws + 8650752);           // 16,777,216 B
    float* ciT         = (float*)(ws + 25427968);                   //   262,144 B
    float* cjT         = (float*)(ws + 25690112);                   //   262,144 B

    kpack_x<<<2048, 256, 0, stream>>>(x, xb);
    kpack_w<<<512, 256, 0, stream>>>(w, wB);
    k_proj<<<BSZ * NN / 32, 256, 0, stream>>>(xb, wB, ai, aj, hB, ciT, cjT);
    k_attn<<<BSZ * (NN / 16), 512, 0, stream>>>(adj, hB, ciT, cjT, bias, out);
}

// Round 5
// 76.462 us; speedup vs baseline: 1.0619x; 1.0619x over previous
//
#include <hip/hip_runtime.h>

#define BSZ 32
#define NN 512
#define INF 256
#define OUTF 128
#define NH 4
#define HD 512
#define NEG_SLOPE 0.2f

typedef __attribute__((ext_vector_type(8))) short bf16x8;
typedef __attribute__((ext_vector_type(8))) unsigned short ushort8;
typedef __attribute__((ext_vector_type(4))) float f32x4;

static __device__ __forceinline__ unsigned short f2bf(float f) {
    unsigned u = __builtin_bit_cast(unsigned, f);
    return (unsigned short)((u + 0x7FFFu + ((u >> 16) & 1u)) >> 16);
}

// ---- pack x -> bf16 row-major [16384][256] ----
__global__ __launch_bounds__(256) void kpack_x(const float* __restrict__ x,
                                               unsigned short* __restrict__ xb) {
    int gid = blockIdx.x * 256 + threadIdx.x;
    const float4* xv = (const float4*)x;
    float4 a = xv[gid * 2], b = xv[gid * 2 + 1];
    ushort8 o;
    o[0]=f2bf(a.x); o[1]=f2bf(a.y); o[2]=f2bf(a.z); o[3]=f2bf(a.w);
    o[4]=f2bf(b.x); o[5]=f2bf(b.y); o[6]=f2bf(b.z); o[7]=f2bf(b.w);
    *(ushort8*)(xb + (size_t)gid * 8) = o;
}

// ---- pack w[256][512] -> wB frag layout ((kb*4+g)*512 + c)*8 + e, k=kb*32+g*8+e ----
__global__ __launch_bounds__(256) void kpack_w(const float* __restrict__ w,
                                               unsigned short* __restrict__ wB) {
    int gid = blockIdx.x * 256 + threadIdx.x;
    int c = gid & 511, k = gid >> 9;
    int kb = k >> 5, g = (k >> 3) & 3, e = k & 7;
    wB[(((size_t)(kb * 4 + g) * 512) + c) * 8 + e] = f2bf(w[(size_t)k * 512 + c]);
}

// ---- projection GEMM (MFMA) + coeffs; hB written via LDS-staged wide stores ----
__global__ __launch_bounds__(256) void k_proj(
    const unsigned short* __restrict__ xb, const unsigned short* __restrict__ wB,
    const float* __restrict__ ai, const float* __restrict__ aj,
    unsigned short* __restrict__ hB, float* __restrict__ ciT, float* __restrict__ cjT)
{
    __shared__ unsigned short hs[NH * 4096];           // 32 KB, hB slab image
    const int tid = threadIdx.x;
    const int lane = tid & 63, head = tid >> 6;
    const int l15 = lane & 15, g = lane >> 4;
    const int row0 = blockIdx.x * 32;

    f32x4 acc[2][8] = {};
    const unsigned short* ap0 = xb + (size_t)(row0 + l15) * INF + g * 8;
    const unsigned short* ap1 = ap0 + 16 * INF;
    const unsigned short* bp  = wB + ((size_t)g * 512 + head * 128 + l15) * 8;

    #pragma unroll
    for (int kb = 0; kb < 8; ++kb) {
        bf16x8 a0 = *(const bf16x8*)(ap0 + kb * 32);
        bf16x8 a1 = *(const bf16x8*)(ap1 + kb * 32);
        #pragma unroll
        for (int nf = 0; nf < 8; ++nf) {
            bf16x8 bv = *(const bf16x8*)(bp + (size_t)kb * 16384 + nf * 128);
            acc[0][nf] = __builtin_amdgcn_mfma_f32_16x16x32_bf16(a0, bv, acc[0][nf], 0, 0, 0);
            acc[1][nf] = __builtin_amdgcn_mfma_f32_16x16x32_bf16(a1, bv, acc[1][nf], 0, 0, 0);
        }
    }

    float aiv[8], ajv[8];
    #pragma unroll
    for (int nf = 0; nf < 8; ++nf) {
        aiv[nf] = ai[head * 128 + nf * 16 + l15];
        ajv[nf] = aj[head * 128 + nf * 16 + l15];
    }
    const int b = row0 >> 9;
    const int nloc0 = row0 & 511;
    const int kb2 = nloc0 >> 5;

    #pragma unroll
    for (int m = 0; m < 2; ++m) {
        float pi[4] = {0,0,0,0}, pj[4] = {0,0,0,0};
        #pragma unroll
        for (int nf = 0; nf < 8; ++nf)
            #pragma unroll
            for (int reg = 0; reg < 4; ++reg) {
                pi[reg] = fmaf(acc[m][nf][reg], aiv[nf], pi[reg]);
                pj[reg] = fmaf(acc[m][nf][reg], ajv[nf], pj[reg]);
            }
        #pragma unroll
        for (int reg = 0; reg < 4; ++reg) {
            #pragma unroll
            for (int off = 1; off < 16; off <<= 1) {
                pi[reg] += __shfl_xor(pi[reg], off);
                pj[reg] += __shfl_xor(pj[reg], off);
            }
        }
        if (l15 == 0) {
            #pragma unroll
            for (int reg = 0; reg < 4; ++reg) {
                int n = nloc0 + 16 * m + 4 * g + reg;
                ciT[((size_t)(head * BSZ + b) * NN) + n] = pi[reg];
                cjT[((size_t)(head * BSZ + b) * NN) + n] = pj[reg];
            }
        }
        #pragma unroll
        for (int reg = 0; reg < 4; ++reg) {
            int jloc = 16 * m + 4 * g + reg;
            int g2 = (jloc >> 3) & 3, e = jloc & 7;
            #pragma unroll
            for (int nf = 0; nf < 8; ++nf)
                hs[head * 4096 + (g2 * 128 + nf * 16 + l15) * 8 + e] =
                    f2bf(acc[m][nf][reg]);
        }
    }
    __syncthreads();
    {
        ushort8* dst = (ushort8*)(hB + (((size_t)(b * 4 + head) * 16 + kb2) * 4096));
        const ushort8* src = (const ushort8*)(hs + head * 4096);
        #pragma unroll
        for (int it = 0; it < 8; ++it)
            dst[it * 64 + lane] = src[it * 64 + lane];
    }
}

// ---- fused masked-softmax attention + MFMA aggregation ----
// 4 pipelined stages (1 head each): in interval s every wave BUILDS P(head s+1)
// into buf^1 (VALU) and GEMMs head s from buf (MFMA) -> both pipes busy per
// interval. Row-sums via ones-MFMA (no shuffles); 1/sum folded into epilogue.
__global__ __launch_bounds__(512, 6) void k_attn(
    const float* __restrict__ adj, const unsigned short* __restrict__ hB,
    const float* __restrict__ ciT, const float* __restrict__ cjT,
    const float* __restrict__ bias, float* __restrict__ out)
{
    __shared__ __align__(16) float cj_s[NH][NN];              // 8 KB
    __shared__ float ci_s[NH][16];
    __shared__ unsigned long long mask_s[16][8];              // 1 KB
    __shared__ float M_s[NH];
    __shared__ __align__(16) unsigned short att_s[2][16 * NN]; // 2 x 16 KB

    const int tid = threadIdx.x;
    const int lane = tid & 63, wave = tid >> 6;
    const int orig = blockIdx.x;
    const int swz = (orig & 7) * 128 + (orig >> 3);   // 1024 % 8 == 0, bijective
    const int b = swz >> 5;
    const int i0 = (swz & 31) * 16;

    #pragma unroll
    for (int hh = 0; hh < NH; ++hh)
        cj_s[hh][tid] = cjT[(size_t)(hh * BSZ + b) * NN + tid];
    if (tid < 64) {
        int r = tid & 15, hh = tid >> 4;
        ci_s[hh][r] = ciT[(size_t)(hh * BSZ + b) * NN + i0 + r];
    }
    #pragma unroll
    for (int rr = 0; rr < 2; ++rr) {
        int r = wave * 2 + rr;
        const float* arow = adj + (size_t)(b * NN + i0 + r) * NN;
        #pragma unroll
        for (int t = 0; t < 8; ++t) {
            unsigned long long msk = __ballot(arow[t * 64 + lane] > 0.f);
            if (lane == 0) mask_s[r][t] = msk;
        }
    }
    __syncthreads();

    if (wave < NH) {   // M_h = unmasked max_j cj[h][j] (upper-bound stabilizer)
        float mv = -1e30f;
        #pragma unroll
        for (int c = 0; c < 8; ++c) mv = fmaxf(mv, cj_s[wave][c * 64 + lane]);
        #pragma unroll
        for (int off = 32; off; off >>= 1) mv = fmaxf(mv, __shfl_xor(mv, off));
        if (lane == 0) M_s[wave] = mv;
    }
    __syncthreads();

    // build P rows {2*wave, 2*wave+1} of head hs into att_s[bi] (unnormalized)
    auto build = [&](int hs, int bi) {
        #pragma unroll
        for (int rr = 0; rr < 2; ++rr) {
            const int r = wave * 2 + rr;
            const unsigned long long* mrow = mask_s[r];
            const float basec = ci_s[hs][r];
            float sm = basec + M_s[hs];
            const float m = fmaxf(sm, NEG_SLOPE * sm);
            char* abase = ((char*)att_s[bi]) + r * 1024;
            const int rx = (r & 7) << 4;
            #pragma unroll
            for (int c = 0; c < 4; ++c) {
                int j2 = c * 128 + lane * 2;
                float2 cv = *(const float2*)&cj_s[hs][j2];
                unsigned bb = (unsigned)((mrow[j2 >> 6] >> (j2 & 63)) & 3ull);
                float s0 = basec + cv.x; s0 = fmaxf(s0, NEG_SLOPE * s0);
                float s1 = basec + cv.y; s1 = fmaxf(s1, NEG_SLOPE * s1);
                float p0 = __expf(s0 - m); p0 = (bb & 1u) ? p0 : 0.f;
                float p1 = __expf(s1 - m); p1 = (bb & 2u) ? p1 : 0.f;
                unsigned pk;
                asm("v_cvt_pk_bf16_f32 %0, %1, %2" : "=v"(pk) : "v"(p0), "v"(p1));
                *(unsigned*)(abase + ((j2 * 2) ^ rx)) = pk;
            }
        }
    };

    build(0, 0);
    __syncthreads();

    const int l15 = lane & 15, g = lane >> 4;
    bf16x8 ones;
    #pragma unroll
    for (int e = 0; e < 8; ++e) ones[e] = (short)0x3F80;   // bf16 1.0

    #pragma unroll
    for (int s = 0; s < 4; ++s) {
        const int bi = s & 1;
        if (s < 3) build(s + 1, bi ^ 1);      // producer work, overlaps GEMM below

        f32x4 acc = {0.f, 0.f, 0.f, 0.f}, accs = {0.f, 0.f, 0.f, 0.f};
        const unsigned short* bp = hB + (size_t)(b * 4 + s) * 65536
                                      + g * 1024 + (wave * 16 + l15) * 8;
        const char* ab = ((const char*)att_s[bi]) + l15 * 1024;
        const int rx2 = (l15 & 7) << 4;

        bf16x8 bcur = *(const bf16x8*)bp;
        #pragma unroll
        for (int kb = 0; kb < 16; ++kb) {
            bf16x8 bnext = bcur;
            if (kb < 15) bnext = *(const bf16x8*)(bp + (size_t)(kb + 1) * 4096);
            bf16x8 av = *(const bf16x8*)(ab + ((kb * 64 + g * 16) ^ rx2));
            acc  = __builtin_amdgcn_mfma_f32_16x16x32_bf16(av, bcur, acc, 0, 0, 0);
            accs = __builtin_amdgcn_mfma_f32_16x16x32_bf16(av, ones, accs, 0, 0, 0);
            bcur = bnext;
        }

        const int colg = s * 128 + wave * 16 + l15;
        const float bvv = bias[colg];
        #pragma unroll
        for (int reg = 0; reg < 4; ++reg) {
            int i = g * 4 + reg;
            float sum = accs[reg];
            float inv = sum > 0.f ? 1.f / sum : 0.f;
            out[(size_t)(b * NN + i0 + i) * HD + colg] = acc[reg] * inv + bvv;
        }
        if (s < 3) __syncthreads();           // buf handoff for next interval
    }
}

extern "C" void kernel_launch(void* const* d_in, const int* in_sizes, int n_in,
                              void* d_out, int out_size, void* d_ws, size_t ws_size,
                              hipStream_t stream)
{
    const float* x    = (const float*)d_in[0];
    const float* adj  = (const float*)d_in[1];
    const float* w    = (const float*)d_in[2];
    const float* ai   = (const float*)d_in[3];
    const float* aj   = (const float*)d_in[4];
    const float* bias = (const float*)d_in[5];
    float* out = (float*)d_out;

    char* ws = (char*)d_ws;
    unsigned short* xb = (unsigned short*)ws;                       // 8,388,608 B
    unsigned short* wB = (unsigned short*)(ws + 8388608);           //   262,144 B
    unsigned short* hB = (unsigned short*)(ws + 8650752);           // 16,777,216 B
    float* ciT         = (float*)(ws + 25427968);                   //   262,144 B
    float* cjT         = (float*)(ws + 25690112);                   //   262,144 B

    kpack_x<<<2048, 256, 0, stream>>>(x, xb);
    kpack_w<<<512, 256, 0, stream>>>(w, wB);
    k_proj<<<BSZ * NN / 32, 256, 0, stream>>>(xb, wB, ai, aj, hB, ciT, cjT);
    k_attn<<<BSZ * (NN / 16), 512, 0, stream>>>(adj, hB, ciT, cjT, bias, out);
}

// Round 6
// 73.782 us; speedup vs baseline: 1.1005x; 1.0363x over previous
//
#include <hip/hip_runtime.h>

#define BSZ 32
#define NN 512
#define INF 256
#define OUTF 128
#define NH 4
#define HD 512
#define NEG_SLOPE 0.2f

typedef __attribute__((ext_vector_type(8))) short bf16x8;
typedef __attribute__((ext_vector_type(4))) float f32x4;

static __device__ __forceinline__ unsigned short f2bf(float f) {
    unsigned u = __builtin_bit_cast(unsigned, f);
    return (unsigned short)((u + 0x7FFFu + ((u >> 16) & 1u)) >> 16);
}

static __device__ __forceinline__ bf16x8 pk8(float4 a, float4 b) {
    unsigned d0, d1, d2, d3;
    asm("v_cvt_pk_bf16_f32 %0, %1, %2" : "=v"(d0) : "v"(a.x), "v"(a.y));
    asm("v_cvt_pk_bf16_f32 %0, %1, %2" : "=v"(d1) : "v"(a.z), "v"(a.w));
    asm("v_cvt_pk_bf16_f32 %0, %1, %2" : "=v"(d2) : "v"(b.x), "v"(b.y));
    asm("v_cvt_pk_bf16_f32 %0, %1, %2" : "=v"(d3) : "v"(b.z), "v"(b.w));
    uint4 u; u.x = d0; u.y = d1; u.z = d2; u.w = d3;
    return __builtin_bit_cast(bf16x8, u);
}

// ---- pack w[256][512] -> wB frag layout ((kb*4+g)*512 + c)*8 + e, k=kb*32+g*8+e ----
__global__ __launch_bounds__(256) void kpack_w(const float* __restrict__ w,
                                               unsigned short* __restrict__ wB) {
    int gid = blockIdx.x * 256 + threadIdx.x;
    int c = gid & 511, k = gid >> 9;
    int kb = k >> 5, g = (k >> 3) & 3, e = k & 7;
    wB[(((size_t)(kb * 4 + g) * 512) + c) * 8 + e] = f2bf(w[(size_t)k * 512 + c]);
}

// ---- projection GEMM (MFMA), fp32 x converted inline; coeffs; hB staged stores ----
__global__ __launch_bounds__(256) void k_proj(
    const float* __restrict__ x, const unsigned short* __restrict__ wB,
    const float* __restrict__ ai, const float* __restrict__ aj,
    unsigned short* __restrict__ hB, float* __restrict__ ciT, float* __restrict__ cjT)
{
    __shared__ unsigned short hs[NH * 4096];           // 32 KB, hB slab image
    const int tid = threadIdx.x;
    const int lane = tid & 63, head = tid >> 6;
    const int l15 = lane & 15, g = lane >> 4;
    const int row0 = blockIdx.x * 32;

    f32x4 acc[2][8] = {};
    const float* xp0 = x + (size_t)(row0 + l15) * INF + g * 8;
    const float* xp1 = xp0 + 16 * INF;
    const unsigned short* bp = wB + ((size_t)g * 512 + head * 128 + l15) * 8;

    #pragma unroll
    for (int kb = 0; kb < 8; ++kb) {
        float4 f0 = *(const float4*)(xp0 + kb * 32);
        float4 f1 = *(const float4*)(xp0 + kb * 32 + 4);
        float4 f2 = *(const float4*)(xp1 + kb * 32);
        float4 f3 = *(const float4*)(xp1 + kb * 32 + 4);
        bf16x8 a0 = pk8(f0, f1);
        bf16x8 a1 = pk8(f2, f3);
        #pragma unroll
        for (int nf = 0; nf < 8; ++nf) {
            bf16x8 bv = *(const bf16x8*)(bp + (size_t)kb * 16384 + nf * 128);
            acc[0][nf] = __builtin_amdgcn_mfma_f32_16x16x32_bf16(a0, bv, acc[0][nf], 0, 0, 0);
            acc[1][nf] = __builtin_amdgcn_mfma_f32_16x16x32_bf16(a1, bv, acc[1][nf], 0, 0, 0);
        }
    }

    float aiv[8], ajv[8];
    #pragma unroll
    for (int nf = 0; nf < 8; ++nf) {
        aiv[nf] = ai[head * 128 + nf * 16 + l15];
        ajv[nf] = aj[head * 128 + nf * 16 + l15];
    }
    const int b = row0 >> 9;
    const int nloc0 = row0 & 511;
    const int kb2 = nloc0 >> 5;

    #pragma unroll
    for (int m = 0; m < 2; ++m) {
        float pi[4] = {0,0,0,0}, pj[4] = {0,0,0,0};
        #pragma unroll
        for (int nf = 0; nf < 8; ++nf)
            #pragma unroll
            for (int reg = 0; reg < 4; ++reg) {
                pi[reg] = fmaf(acc[m][nf][reg], aiv[nf], pi[reg]);
                pj[reg] = fmaf(acc[m][nf][reg], ajv[nf], pj[reg]);
            }
        #pragma unroll
        for (int reg = 0; reg < 4; ++reg) {
            #pragma unroll
            for (int off = 1; off < 16; off <<= 1) {
                pi[reg] += __shfl_xor(pi[reg], off);
                pj[reg] += __shfl_xor(pj[reg], off);
            }
        }
        if (l15 == 0) {
            #pragma unroll
            for (int reg = 0; reg < 4; ++reg) {
                int n = nloc0 + 16 * m + 4 * g + reg;
                ciT[((size_t)(head * BSZ + b) * NN) + n] = pi[reg];
                cjT[((size_t)(head * BSZ + b) * NN) + n] = pj[reg];
            }
        }
        #pragma unroll
        for (int reg = 0; reg < 4; ++reg) {
            int jloc = 16 * m + 4 * g + reg;
            int g2 = (jloc >> 3) & 3, e = jloc & 7;
            #pragma unroll
            for (int nf = 0; nf < 8; ++nf)
                hs[head * 4096 + (g2 * 128 + nf * 16 + l15) * 8 + e] =
                    f2bf(acc[m][nf][reg]);
        }
    }
    __syncthreads();
    {
        typedef __attribute__((ext_vector_type(8))) unsigned short ushort8;
        ushort8* dst = (ushort8*)(hB + (((size_t)(b * 4 + head) * 16 + kb2) * 4096));
        const ushort8* src = (const ushort8*)(hs + head * 4096);
        #pragma unroll
        for (int it = 0; it < 8; ++it)
            dst[it * 64 + lane] = src[it * 64 + lane];
    }
}

// ---- fused attention: P built per-lane in A-frag layout (no LDS round-trip,
// no barriers in main loop). Wave = 1 head x 2 i-tiles (32 rows); B-frags
// shared across tiles. Row-sums via ones-MFMA; 1/sum in epilogue.
__global__ __launch_bounds__(256) void k_attn(
    const float* __restrict__ adj, const unsigned short* __restrict__ hB,
    const float* __restrict__ ciT, const float* __restrict__ cjT,
    const float* __restrict__ bias, float* __restrict__ out)
{
    __shared__ __align__(16) float cj_s[NH][NN];   // 8 KB
    __shared__ float ci_s[NH][32];
    __shared__ unsigned maskw[32][17];             // padded: conflict-free b32 reads
    __shared__ float M_s[NH];

    const int tid = threadIdx.x;
    const int lane = tid & 63, h = tid >> 6;
    const int l15 = lane & 15, g = lane >> 4;

    const int orig = blockIdx.x;                   // 512 blocks, 512%8==0 bijective
    const int swz = (orig & 7) * 64 + (orig >> 3); // XCD chunking: 4 b's per XCD
    const int b = swz >> 4;
    const int i0 = (swz & 15) * 32;

    {   // cj for this head + unmasked max (softmax stabilizer upper bound)
        const float* src = cjT + (size_t)(h * BSZ + b) * NN;
        float mv = -1e30f;
        #pragma unroll
        for (int c = 0; c < 8; ++c) {
            float v = src[c * 64 + lane];
            cj_s[h][c * 64 + lane] = v;
            mv = fmaxf(mv, v);
        }
        #pragma unroll
        for (int off = 32; off; off >>= 1) mv = fmaxf(mv, __shfl_xor(mv, off));
        if (lane == 0) M_s[h] = mv;
        if (lane < 32) ci_s[h][lane] = ciT[(size_t)(h * BSZ + b) * NN + i0 + lane];
    }
    // adjacency -> 32-bit mask words; wave h builds rows h*8..h*8+7
    #pragma unroll
    for (int rr = 0; rr < 8; ++rr) {
        int r = h * 8 + rr;
        const float* arow = adj + (size_t)(b * NN + i0 + r) * NN;
        #pragma unroll
        for (int t = 0; t < 8; ++t) {
            unsigned long long msk = __ballot(arow[t * 64 + lane] > 0.f);
            if (lane == 0) {
                maskw[r][2 * t]     = (unsigned)msk;
                maskw[r][2 * t + 1] = (unsigned)(msk >> 32);
            }
        }
    }
    __syncthreads();

    const float Mh = M_s[h];
    float bc[2], mrow[2];
    #pragma unroll
    for (int t = 0; t < 2; ++t) {
        bc[t] = ci_s[h][t * 16 + l15];             // this lane's A-row ci
        float sm = bc[t] + Mh;
        mrow[t] = fmaxf(sm, NEG_SLOPE * sm);       // upper bound of row's leaky scores
    }
    float bv[8];
    #pragma unroll
    for (int nf = 0; nf < 8; ++nf) bv[nf] = bias[h * 128 + nf * 16 + l15];

    bf16x8 ones;
    #pragma unroll
    for (int e = 0; e < 8; ++e) ones[e] = (short)0x3F80;

    f32x4 acc[2][8] = {};
    f32x4 accs[2] = {};
    const unsigned short* bp = hB + (size_t)(b * 4 + h) * 65536 + g * 1024 + l15 * 8;
    const float* cjh = cj_s[h];

    #pragma unroll 2
    for (int kb = 0; kb < 16; ++kb) {
        bf16x8 bf[8];
        #pragma unroll
        for (int nf = 0; nf < 8; ++nf)
            bf[nf] = *(const bf16x8*)(bp + (size_t)kb * 4096 + nf * 128);

        float4 cva = *(const float4*)&cjh[kb * 32 + g * 8];
        float4 cvb = *(const float4*)&cjh[kb * 32 + g * 8 + 4];
        float cj8[8] = {cva.x, cva.y, cva.z, cva.w, cvb.x, cvb.y, cvb.z, cvb.w};

        #pragma unroll
        for (int t = 0; t < 2; ++t) {
            unsigned byte = (maskw[t * 16 + l15][kb] >> (g * 8)) & 0xFFu;
            float p[8];
            #pragma unroll
            for (int e = 0; e < 8; ++e) {
                float s = bc[t] + cj8[e];
                s = fmaxf(s, NEG_SLOPE * s);
                float pe = __expf(s - mrow[t]);
                p[e] = ((byte >> e) & 1u) ? pe : 0.f;
            }
            unsigned d0, d1, d2, d3;
            asm("v_cvt_pk_bf16_f32 %0, %1, %2" : "=v"(d0) : "v"(p[0]), "v"(p[1]));
            asm("v_cvt_pk_bf16_f32 %0, %1, %2" : "=v"(d1) : "v"(p[2]), "v"(p[3]));
            asm("v_cvt_pk_bf16_f32 %0, %1, %2" : "=v"(d2) : "v"(p[4]), "v"(p[5]));
            asm("v_cvt_pk_bf16_f32 %0, %1, %2" : "=v"(d3) : "v"(p[6]), "v"(p[7]));
            uint4 u; u.x = d0; u.y = d1; u.z = d2; u.w = d3;
            bf16x8 av = __builtin_bit_cast(bf16x8, u);

            #pragma unroll
            for (int nf = 0; nf < 8; ++nf)
                acc[t][nf] = __builtin_amdgcn_mfma_f32_16x16x32_bf16(av, bf[nf], acc[t][nf], 0, 0, 0);
            accs[t] = __builtin_amdgcn_mfma_f32_16x16x32_bf16(av, ones, accs[t], 0, 0, 0);
        }
    }

    #pragma unroll
    for (int t = 0; t < 2; ++t) {
        #pragma unroll
        for (int reg = 0; reg < 4; ++reg) {
            float sum = accs[t][reg];
            float inv = sum > 0.f ? 1.f / sum : 0.f;
            const int i = i0 + t * 16 + g * 4 + reg;   // D row = g*4+reg
            #pragma unroll
            for (int nf = 0; nf < 8; ++nf) {
                int colg = h * 128 + nf * 16 + l15;
                out[(size_t)(b * NN + i) * HD + colg] = acc[t][nf][reg] * inv + bv[nf];
            }
        }
    }
}

extern "C" void kernel_launch(void* const* d_in, const int* in_sizes, int n_in,
                              void* d_out, int out_size, void* d_ws, size_t ws_size,
                              hipStream_t stream)
{
    const float* x    = (const float*)d_in[0];
    const float* adj  = (const float*)d_in[1];
    const float* w    = (const float*)d_in[2];
    const float* ai   = (const float*)d_in[3];
    const float* aj   = (const float*)d_in[4];
    const float* bias = (const float*)d_in[5];
    float* out = (float*)d_out;

    char* ws = (char*)d_ws;
    unsigned short* wB = (unsigned short*)ws;                       //   262,144 B
    unsigned short* hB = (unsigned short*)(ws + 262144);            // 16,777,216 B
    float* ciT         = (float*)(ws + 17039360);                   //   262,144 B
    float* cjT         = (float*)(ws + 17301504);                   //   262,144 B

    kpack_w<<<512, 256, 0, stream>>>(w, wB);
    k_proj<<<BSZ * NN / 32, 256, 0, stream>>>(x, wB, ai, aj, hB, ciT, cjT);
    k_attn<<<BSZ * (NN / 32), 256, 0, stream>>>(adj, hB, ciT, cjT, bias, out);
}